// Round 3
// baseline (1449.361 us; speedup 1.0000x reference)
//
#include <hip/hip_runtime.h>

// ---- problem constants ----
#define SIZE   48
#define DESIZE 44
#define PAD    3
#define BATCH  4
#define FLAT   (DESIZE*SIZE*SIZE)      // 101376
#define CVOL   216                     // 6*6*6

// stencil tile: 1 (i) x 4 (j) x 16 (k) voxels, 64 voxels, ALL 4 batches
#define TJ 4
#define TK 16
#define NA 6
#define NB (TJ+5)                      // 9
#define NC (TK+5)                      // 21
#define NEU_T (NA*NB*NC)               // 1134 halo elements (float4 over batches)
#define NTILE 1584                     // 44*36
#define NBLK  768                      // persistent grid: exactly 3 blocks/CU; capacity @(256,4) = 1024

// MLP1 split-K
#define KSLICE  96
#define NSLICES (FLAT/KSLICE)          // 1056

// Each warp handles a contiguous slice of the 54 float4-chunks of its lane's
// synapse row (R1-style direct per-lane loads; rows are 864B contiguous).
template <int CBASE, int CNT>
__device__ __forceinline__ void do_chunk4(const float4* __restrict__ rp,
                                          const float4* __restrict__ neu4,
                                          int lanebase, float acc[4]) {
    constexpr int H1n = (CNT + 1) / 2;
    constexpr int H2n = CNT - H1n;
    {
        float4 sr[H1n];
#pragma unroll
        for (int s2 = 0; s2 < H1n; ++s2) sr[s2] = rp[CBASE + s2];
#pragma unroll
        for (int s2 = 0; s2 < H1n; ++s2) {
#pragma unroll
            for (int j = 0; j < 4; ++j) {
                const int c   = (CBASE + s2) * 4 + j;
                const int off = (c / 36) * (NB * NC) + ((c % 36) / 6) * NC + (c % 6);
                const float wv = (&sr[s2].x)[j];
                const float4 n4 = neu4[lanebase + off];        // ds_read_b128
                acc[0] += wv * n4.x; acc[1] += wv * n4.y;
                acc[2] += wv * n4.z; acc[3] += wv * n4.w;
            }
        }
    }
    {
        float4 sr[H2n];
#pragma unroll
        for (int s2 = 0; s2 < H2n; ++s2) sr[s2] = rp[CBASE + H1n + s2];
#pragma unroll
        for (int s2 = 0; s2 < H2n; ++s2) {
#pragma unroll
            for (int j = 0; j < 4; ++j) {
                const int c   = (CBASE + H1n + s2) * 4 + j;
                const int off = (c / 36) * (NB * NC) + ((c % 36) / 6) * NC + (c % 6);
                const float wv = (&sr[s2].x)[j];
                const float4 n4 = neu4[lanebase + off];
                acc[0] += wv * n4.x; acc[1] += wv * n4.y;
                acc[2] += wv * n4.z; acc[3] += wv * n4.w;
            }
        }
    }
}

// Grid-wide barrier: all NBLK blocks co-resident (capacity 1024 > 768 by
// construction). Agent-scope fences handle cross-XCD L2 non-coherence (G16).
__device__ __forceinline__ void gbar(int* bar) {
    __syncthreads();                       // drains vmcnt: all block stores in L2
    if (threadIdx.x == 0) {
        __threadfence();                   // agent release: wbL2 to coherence point
        int g = __hip_atomic_load(bar + 1, __ATOMIC_RELAXED, __HIP_MEMORY_SCOPE_AGENT);
        if (atomicAdd(bar, 1) == NBLK - 1) {
            __hip_atomic_store(bar, 0, __ATOMIC_RELAXED, __HIP_MEMORY_SCOPE_AGENT);
            __hip_atomic_fetch_add(bar + 1, 1, __ATOMIC_RELEASE, __HIP_MEMORY_SCOPE_AGENT);
        } else {
            while (__hip_atomic_load(bar + 1, __ATOMIC_ACQUIRE, __HIP_MEMORY_SCOPE_AGENT) == g)
                __builtin_amdgcn_s_sleep(2);
        }
        __threadfence();                   // agent acquire: invalidate stale L1/L2
    }
    __syncthreads();
}

__global__ void k_init(int* __restrict__ p) {
    if (threadIdx.x < 8) p[threadIdx.x] = 0;
}

// All 5 stencil steps in ONE persistent kernel. Dynamic tile claim per step
// (perfect balance), grid barrier between steps. dst ping-pong: A,B,A,B,A.
__global__ __launch_bounds__(256, 4) void k_fused(const float* __restrict__ vin,
                                                  const float* __restrict__ frame,
                                                  const float* __restrict__ syn,
                                                  float4* __restrict__ A4,
                                                  float4* __restrict__ B4,
                                                  int* __restrict__ bar,
                                                  int* __restrict__ ctr) {
    __shared__ float4 neu4[NEU_T];            // 18144 B
    __shared__ float  part[4 * 256];          //  4096 B
    __shared__ int    s_tile;
    int t = threadIdx.x;

    for (int s = 0; s < 5; ++s) {
        const float4* src4 = (s & 1) ? A4 : B4;   // unused when s==0
        float4*       dst4 = (s & 1) ? B4 : A4;

        for (;;) {
            if (t == 0) s_tile = atomicAdd(&ctr[s], 1);
            __syncthreads();
            int r = s_tile;
            if (r >= NTILE) break;

            int i0 = r / 36;
            int r2 = r % 36;
            int j0 = (r2 / 3) * TJ;
            int k0 = (r2 % 3) * TK;

            // stage neu halo (6x9x21), zero-padded
            for (int e = t; e < NEU_T; e += 256) {
                int a   = e / (NB * NC);
                int rem = e % (NB * NC);
                int jj  = rem / NC;
                int cc  = rem % NC;
                int gi = i0 + a - PAD;
                int gj = j0 + jj - PAD;
                int gk = k0 + cc - PAD;
                float4 vv = make_float4(0.f, 0.f, 0.f, 0.f);
                if ((unsigned)gi < DESIZE && (unsigned)gj < SIZE && (unsigned)gk < SIZE) {
                    int idx = (gi * SIZE + gj) * SIZE + gk;
                    if (s == 0) {
                        float fr = frame[idx];
                        vv.x = vin[0 * FLAT + idx] + fr;
                        vv.y = vin[1 * FLAT + idx] + fr;
                        vv.z = vin[2 * FLAT + idx] + fr;
                        vv.w = vin[3 * FLAT + idx] + fr;
                    } else {
                        vv = src4[idx];
                    }
                }
                neu4[e] = vv;
            }
            __syncthreads();

            int w = t >> 6, l = t & 63;
            int dj = l >> 4, dk = l & 15;
            int lanebase = dj * NC + dk;
            const float4* rp = (const float4*)(syn +
                (size_t)((i0 * SIZE + j0 + dj) * SIZE + k0 + dk) * CVOL);

            float acc[4] = {0.f, 0.f, 0.f, 0.f};
            switch (w) {
                case 0:  do_chunk4< 0, 14>(rp, neu4, lanebase, acc); break;
                case 1:  do_chunk4<14, 14>(rp, neu4, lanebase, acc); break;
                case 2:  do_chunk4<28, 13>(rp, neu4, lanebase, acc); break;
                default: do_chunk4<41, 13>(rp, neu4, lanebase, acc); break;
            }
#pragma unroll
            for (int bb = 0; bb < 4; ++bb) part[bb * 256 + t] = acc[bb];
            __syncthreads();

            if (t < 64) {
                float4 o;
                o.x = part[  0 + t] + part[  0 + 64 + t] + part[  0 + 128 + t] + part[  0 + 192 + t];
                o.y = part[256 + t] + part[256 + 64 + t] + part[256 + 128 + t] + part[256 + 192 + t];
                o.z = part[512 + t] + part[512 + 64 + t] + part[512 + 128 + t] + part[512 + 192 + t];
                o.w = part[768 + t] + part[768 + 64 + t] + part[768 + 128 + t] + part[768 + 192 + t];
                o.x = fmaxf(o.x, 0.f) * 0.9f;
                o.y = fmaxf(o.y, 0.f) * 0.9f;
                o.z = fmaxf(o.z, 0.f) * 0.9f;
                o.w = fmaxf(o.w, 0.f) * 0.9f;
                int dj2 = t >> 4, dk2 = t & 15;
                dst4[(i0 * SIZE + (j0 + dj2)) * SIZE + (k0 + dk2)] = o;
            }
            // next tile's staging (neu4 writes) is safe: all neu4 reads ended
            // before the part-sync above; part readers (t<64) don't touch neu4.
        }
        if (s < 4) gbar(bar);
    }
}

// x4 (FLAT x [4 batches]) @ W1 (FLAT x 1024), split-K. 256 thr, 4 cols/thread.
__global__ __launch_bounds__(256) void k_mlp1(const float4* __restrict__ x4,
                                              const float* __restrict__ W1,
                                              float* __restrict__ partial) {
    __shared__ float xs[KSLICE * 4];   // [kk][b] == float4 per kk
    int t = threadIdx.x;
    int s = blockIdx.x;
    int k0 = s * KSLICE;
    for (int e = t; e < KSLICE; e += 256)
        ((float4*)xs)[e] = x4[k0 + e];
    __syncthreads();
    float acc[4][4] = {};
    const float* wp = W1 + (size_t)k0 * 1024 + t * 4;
#pragma unroll 8
    for (int kk = 0; kk < KSLICE; ++kk) {
        float4 w  = *(const float4*)(wp + (size_t)kk * 1024);
        float4 xv = *(const float4*)(xs + kk * 4);
        acc[0][0] += xv.x * w.x; acc[0][1] += xv.x * w.y; acc[0][2] += xv.x * w.z; acc[0][3] += xv.x * w.w;
        acc[1][0] += xv.y * w.x; acc[1][1] += xv.y * w.y; acc[1][2] += xv.y * w.z; acc[1][3] += xv.y * w.w;
        acc[2][0] += xv.z * w.x; acc[2][1] += xv.z * w.y; acc[2][2] += xv.z * w.z; acc[2][3] += xv.z * w.w;
        acc[3][0] += xv.w * w.x; acc[3][1] += xv.w * w.y; acc[3][2] += xv.w * w.z; acc[3][3] += xv.w * w.w;
    }
#pragma unroll
    for (int b = 0; b < 4; ++b) {
        float4 o = make_float4(acc[b][0], acc[b][1], acc[b][2], acc[b][3]);
        *(float4*)(partial + (size_t)s * 4096 + b * 1024 + t * 4) = o;
    }
}

// reduce NSLICES partials -> h1 = relu(sum + b1). 256 blocks x 256 thr.
__global__ __launch_bounds__(256) void k_reduce1(const float* __restrict__ partial,
                                                 const float* __restrict__ b1,
                                                 float* __restrict__ h1) {
    __shared__ float red[16][17];
    int t = threadIdx.x;
    int e0 = blockIdx.x * 16;
    int eo = t & 15, sl = t >> 4;
    float acc = 0.f;
    for (int it = 0; it < NSLICES / 16; ++it) {
        int s = sl + 16 * it;
        acc += partial[(size_t)s * 4096 + e0 + eo];
    }
    red[sl][eo] = acc;
    __syncthreads();
    if (t < 16) {
        float a = 0.f;
#pragma unroll
        for (int rr = 0; rr < 16; ++rr) a += red[rr][t];
        int e = e0 + t;
        h1[e] = fmaxf(a + b1[e & 1023], 0.f);
    }
}

// h1 (4x1024) @ W2 (1024x128), split-K 32 x 2 col-chunks, 64 thr. grid=64.
__global__ __launch_bounds__(64) void k_mlp2(const float* __restrict__ h1,
                                             const float* __restrict__ W2,
                                             float* __restrict__ partial2) {
    __shared__ float xs[32 * 4];
    int t = threadIdx.x;
    int bid = blockIdx.x;
    int s = bid >> 1, ch = bid & 1;
    int k0 = s * 32;
    for (int e = t; e < 128; e += 64) {
        int kk = e >> 2, b = e & 3;
        xs[e] = h1[b * 1024 + k0 + kk];
    }
    __syncthreads();
    float acc[4] = {0.f, 0.f, 0.f, 0.f};
    int n2 = ch * 64 + t;
#pragma unroll
    for (int kk = 0; kk < 32; ++kk) {
        float w = W2[(size_t)(k0 + kk) * 128 + n2];
        float4 xv = *(const float4*)(xs + kk * 4);
        acc[0] += xv.x * w; acc[1] += xv.y * w; acc[2] += xv.z * w; acc[3] += xv.w * w;
    }
#pragma unroll
    for (int b = 0; b < 4; ++b) partial2[s * 512 + b * 128 + n2] = acc[b];
}

__global__ __launch_bounds__(128) void k_mlp3(const float* __restrict__ partial2,
                                              const float* __restrict__ b2,
                                              const float* __restrict__ W3,
                                              const float* __restrict__ b3,
                                              float* __restrict__ out) {
    __shared__ float h2[512];   // [b][n2]
    int t = threadIdx.x;
    for (int e = t; e < 512; e += 128) {
        int n2 = e & 127;
        float a = b2[n2];
#pragma unroll 8
        for (int s = 0; s < 32; ++s) a += partial2[s * 512 + e];
        h2[e] = fmaxf(a, 0.f);
    }
    __syncthreads();
    if (t < 40) {
        int b = t / 10, o = t % 10;
        float a = b3[o];
        for (int k = 0; k < 128; ++k) a += h2[b * 128 + k] * W3[k * 10 + o];
        out[b * 10 + o] = a;
    }
}

extern "C" void kernel_launch(void* const* d_in, const int* in_sizes, int n_in,
                              void* d_out, int out_size, void* d_ws, size_t ws_size,
                              hipStream_t stream) {
    const float* vin   = (const float*)d_in[0];
    const float* frame = (const float*)d_in[1];
    const float* syn   = (const float*)d_in[2];
    const float* W1    = (const float*)d_in[3];
    const float* b1    = (const float*)d_in[4];
    const float* W2    = (const float*)d_in[5];
    const float* b2    = (const float*)d_in[6];
    const float* W3    = (const float*)d_in[7];
    const float* b3    = (const float*)d_in[8];
    float* out = (float*)d_out;

    int*   ibase = (int*)d_ws;                // bar[2] + ctr[5] (zeroed per iter)
    float* ws    = (float*)d_ws + 16;         // 64B-aligned float region
    float* A   = ws;                          // FLAT float4 = 405504 floats
    float* B   = A + (size_t)BATCH * FLAT;
    float* P1  = B + (size_t)BATCH * FLAT;    // 1056*4096
    float* H1  = P1 + (size_t)NSLICES * 4096; // 4096
    float* P2  = H1 + 4096;                   // 16384

    k_init<<<1, 64, 0, stream>>>(ibase);
    k_fused<<<NBLK, 256, 0, stream>>>(vin, frame, syn,
                                      (float4*)A, (float4*)B, ibase, ibase + 2);

    k_mlp1<<<NSLICES, 256, 0, stream>>>((const float4*)A, W1, P1);
    k_reduce1<<<256, 256, 0, stream>>>(P1, b1, H1);
    k_mlp2<<<64, 64, 0, stream>>>(H1, W2, P2);
    k_mlp3<<<1, 128, 0, stream>>>(P2, b2, W3, b3, out);
}

// Round 6
// 701.006 us; speedup vs baseline: 2.0675x; 2.0675x over previous
//
#include <hip/hip_runtime.h>

// ---- problem constants ----
#define SIZE   48
#define DESIZE 44
#define PAD    3
#define BATCH  4
#define FLAT   (DESIZE*SIZE*SIZE)      // 101376
#define CVOL   216                     // 6*6*6

// stencil tile: 1 (i) x 4 (j) x 16 (k) voxels per block, 64 voxels, ALL 4 batches
#define TJ 4
#define TK 16
#define NA 6
#define NB (TJ+5)                      // 9
#define NC (TK+5)                      // 21
#define NEU_T (NA*NB*NC)               // 1134 halo elements (float4 over batches)
#define NTILE 1584                     // 44*36

// MLP1 split-K: 132*768 = 101376 -> grid 768 = exactly 3 blocks/CU (no tail round)
#define KSLICE  132
#define NSLICES (FLAT/KSLICE)          // 768

// Each warp handles a contiguous slice of the 54 float4-chunks of its lane's
// synapse row, held in VGPRs (rows are 864B contiguous; L1 captures the stream).
template <int CBASE, int CNT>
__device__ __forceinline__ void do_chunk4(const float4* __restrict__ rp,
                                          const float4* __restrict__ neu4,
                                          int lanebase, float acc[4]) {
    constexpr int H1n = (CNT + 1) / 2;
    constexpr int H2n = CNT - H1n;
    {
        float4 sr[H1n];
#pragma unroll
        for (int s2 = 0; s2 < H1n; ++s2) sr[s2] = rp[CBASE + s2];
#pragma unroll
        for (int s2 = 0; s2 < H1n; ++s2) {
#pragma unroll
            for (int j = 0; j < 4; ++j) {
                const int c   = (CBASE + s2) * 4 + j;
                const int off = (c / 36) * (NB * NC) + ((c % 36) / 6) * NC + (c % 6);
                const float wv = (&sr[s2].x)[j];
                const float4 n4 = neu4[lanebase + off];        // ds_read_b128
                acc[0] += wv * n4.x; acc[1] += wv * n4.y;
                acc[2] += wv * n4.z; acc[3] += wv * n4.w;
            }
        }
    }
    {
        float4 sr[H2n];
#pragma unroll
        for (int s2 = 0; s2 < H2n; ++s2) sr[s2] = rp[CBASE + H1n + s2];
#pragma unroll
        for (int s2 = 0; s2 < H2n; ++s2) {
#pragma unroll
            for (int j = 0; j < 4; ++j) {
                const int c   = (CBASE + H1n + s2) * 4 + j;
                const int off = (c / 36) * (NB * NC) + ((c % 36) / 6) * NC + (c % 6);
                const float wv = (&sr[s2].x)[j];
                const float4 n4 = neu4[lanebase + off];
                acc[0] += wv * n4.x; acc[1] += wv * n4.y;
                acc[2] += wv * n4.z; acc[3] += wv * n4.w;
            }
        }
    }
}

// One block = one 64-voxel tile x ALL 4 batches. grid = 1584.
// neu carried between steps as float4[FLAT] = [idx][batch].
template <bool FIRST>
__global__ __launch_bounds__(256, 4) void k_step(const float4* __restrict__ nin4,
                                                 const float* __restrict__ vin,
                                                 const float* __restrict__ frame,
                                                 const float* __restrict__ syn,
                                                 float4* __restrict__ nout4) {
    __shared__ float4 neu4[NEU_T];            // 18144 B
    __shared__ float  part[4 * 256];          //  4096 B
    int t  = threadIdx.x;
    int r  = blockIdx.x;
    int i0 = r / 36;
    int r2 = r % 36;
    int j0 = (r2 / 3) * TJ;
    int k0 = (r2 % 3) * TK;

    // stage neu halo (6x9x21), zero-padded, 1 coalesced dwordx4 per element
    for (int e = t; e < NEU_T; e += 256) {
        int a   = e / (NB * NC);
        int rem = e % (NB * NC);
        int jj  = rem / NC;
        int cc  = rem % NC;
        int gi = i0 + a - PAD;
        int gj = j0 + jj - PAD;
        int gk = k0 + cc - PAD;
        float4 vv = make_float4(0.f, 0.f, 0.f, 0.f);
        if ((unsigned)gi < DESIZE && (unsigned)gj < SIZE && (unsigned)gk < SIZE) {
            int idx = (gi * SIZE + gj) * SIZE + gk;
            if (FIRST) {
                float fr = frame[idx];
                vv.x = vin[0 * FLAT + idx] + fr;
                vv.y = vin[1 * FLAT + idx] + fr;
                vv.z = vin[2 * FLAT + idx] + fr;
                vv.w = vin[3 * FLAT + idx] + fr;
            } else {
                vv = nin4[idx];
            }
        }
        neu4[e] = vv;
    }
    __syncthreads();

    int w = t >> 6, l = t & 63;
    int dj = l >> 4, dk = l & 15;
    int lanebase = dj * NC + dk;
    const float4* rp = (const float4*)(syn +
        (size_t)((i0 * SIZE + j0 + dj) * SIZE + k0 + dk) * CVOL);

    float acc[4] = {0.f, 0.f, 0.f, 0.f};
    switch (w) {
        case 0:  do_chunk4< 0, 14>(rp, neu4, lanebase, acc); break;
        case 1:  do_chunk4<14, 14>(rp, neu4, lanebase, acc); break;
        case 2:  do_chunk4<28, 13>(rp, neu4, lanebase, acc); break;
        default: do_chunk4<41, 13>(rp, neu4, lanebase, acc); break;
    }
#pragma unroll
    for (int bb = 0; bb < 4; ++bb) part[bb * 256 + t] = acc[bb];
    __syncthreads();

    // 64 finals: one voxel each, float4 over batches, coalesced store
    if (t < 64) {
        float4 o;
        o.x = part[  0 + t] + part[  0 + 64 + t] + part[  0 + 128 + t] + part[  0 + 192 + t];
        o.y = part[256 + t] + part[256 + 64 + t] + part[256 + 128 + t] + part[256 + 192 + t];
        o.z = part[512 + t] + part[512 + 64 + t] + part[512 + 128 + t] + part[512 + 192 + t];
        o.w = part[768 + t] + part[768 + 64 + t] + part[768 + 128 + t] + part[768 + 192 + t];
        o.x = fmaxf(o.x, 0.f) * 0.9f;
        o.y = fmaxf(o.y, 0.f) * 0.9f;
        o.z = fmaxf(o.z, 0.f) * 0.9f;
        o.w = fmaxf(o.w, 0.f) * 0.9f;
        int dj2 = t >> 4, dk2 = t & 15;
        nout4[(i0 * SIZE + (j0 + dj2)) * SIZE + (k0 + dk2)] = o;
    }
}

// x4 (FLAT x [4 batches]) @ W1 (FLAT x 1024), split-K. 256 thr, 4 cols/thread.
// KSLICE=132 -> 768 blocks = exactly 3/CU (no occupancy-quantization tail).
__global__ __launch_bounds__(256) void k_mlp1(const float4* __restrict__ x4,
                                              const float* __restrict__ W1,
                                              float* __restrict__ partial) {
    __shared__ float xs[KSLICE * 4];   // [kk][b] == float4 per kk
    int t = threadIdx.x;
    int s = blockIdx.x;
    int k0 = s * KSLICE;
    for (int e = t; e < KSLICE; e += 256)
        ((float4*)xs)[e] = x4[k0 + e];
    __syncthreads();
    float acc[4][4] = {};
    const float4* wp = (const float4*)(W1 + (size_t)k0 * 1024) + t;
#pragma unroll 6
    for (int kk = 0; kk < KSLICE; ++kk) {
        float4 w  = wp[(size_t)kk * 256];
        float4 xv = *(const float4*)(xs + kk * 4);
        acc[0][0] += xv.x * w.x; acc[0][1] += xv.x * w.y; acc[0][2] += xv.x * w.z; acc[0][3] += xv.x * w.w;
        acc[1][0] += xv.y * w.x; acc[1][1] += xv.y * w.y; acc[1][2] += xv.y * w.z; acc[1][3] += xv.y * w.w;
        acc[2][0] += xv.z * w.x; acc[2][1] += xv.z * w.y; acc[2][2] += xv.z * w.z; acc[2][3] += xv.z * w.w;
        acc[3][0] += xv.w * w.x; acc[3][1] += xv.w * w.y; acc[3][2] += xv.w * w.z; acc[3][3] += xv.w * w.w;
    }
#pragma unroll
    for (int b = 0; b < 4; ++b) {
        float4 o = make_float4(acc[b][0], acc[b][1], acc[b][2], acc[b][3]);
        *(float4*)(partial + (size_t)s * 4096 + b * 1024 + t * 4) = o;
    }
}

// reduce NSLICES partials -> h1 = relu(sum + b1). 256 blocks x 256 thr.
__global__ __launch_bounds__(256) void k_reduce1(const float* __restrict__ partial,
                                                 const float* __restrict__ b1,
                                                 float* __restrict__ h1) {
    __shared__ float red[16][17];
    int t = threadIdx.x;
    int e0 = blockIdx.x * 16;
    int eo = t & 15, sl = t >> 4;
    float acc = 0.f;
    for (int it = 0; it < NSLICES / 16; ++it) {
        int s = sl + 16 * it;
        acc += partial[(size_t)s * 4096 + e0 + eo];
    }
    red[sl][eo] = acc;
    __syncthreads();
    if (t < 16) {
        float a = 0.f;
#pragma unroll
        for (int rr = 0; rr < 16; ++rr) a += red[rr][t];
        int e = e0 + t;
        h1[e] = fmaxf(a + b1[e & 1023], 0.f);
    }
}

// h1 (4x1024) @ W2 (1024x128), split-K 32 x 2 col-chunks, 64 thr. grid=64.
__global__ __launch_bounds__(64) void k_mlp2(const float* __restrict__ h1,
                                             const float* __restrict__ W2,
                                             float* __restrict__ partial2) {
    __shared__ float xs[32 * 4];
    int t = threadIdx.x;
    int bid = blockIdx.x;
    int s = bid >> 1, ch = bid & 1;
    int k0 = s * 32;
    for (int e = t; e < 128; e += 64) {
        int kk = e >> 2, b = e & 3;
        xs[e] = h1[b * 1024 + k0 + kk];
    }
    __syncthreads();
    float acc[4] = {0.f, 0.f, 0.f, 0.f};
    int n2 = ch * 64 + t;
#pragma unroll
    for (int kk = 0; kk < 32; ++kk) {
        float w = W2[(size_t)(k0 + kk) * 128 + n2];
        float4 xv = *(const float4*)(xs + kk * 4);
        acc[0] += xv.x * w; acc[1] += xv.y * w; acc[2] += xv.z * w; acc[3] += xv.w * w;
    }
#pragma unroll
    for (int b = 0; b < 4; ++b) partial2[s * 512 + b * 128 + n2] = acc[b];
}

__global__ __launch_bounds__(128) void k_mlp3(const float* __restrict__ partial2,
                                              const float* __restrict__ b2,
                                              const float* __restrict__ W3,
                                              const float* __restrict__ b3,
                                              float* __restrict__ out) {
    __shared__ float h2[512];   // [b][n2]
    int t = threadIdx.x;
    for (int e = t; e < 512; e += 128) {
        int n2 = e & 127;
        float a = b2[n2];
#pragma unroll 8
        for (int s = 0; s < 32; ++s) a += partial2[s * 512 + e];
        h2[e] = fmaxf(a, 0.f);
    }
    __syncthreads();
    if (t < 40) {
        int b = t / 10, o = t % 10;
        float a = b3[o];
        for (int k = 0; k < 128; ++k) a += h2[b * 128 + k] * W3[k * 10 + o];
        out[b * 10 + o] = a;
    }
}

extern "C" void kernel_launch(void* const* d_in, const int* in_sizes, int n_in,
                              void* d_out, int out_size, void* d_ws, size_t ws_size,
                              hipStream_t stream) {
    const float* vin   = (const float*)d_in[0];
    const float* frame = (const float*)d_in[1];
    const float* syn   = (const float*)d_in[2];
    const float* W1    = (const float*)d_in[3];
    const float* b1    = (const float*)d_in[4];
    const float* W2    = (const float*)d_in[5];
    const float* b2    = (const float*)d_in[6];
    const float* W3    = (const float*)d_in[7];
    const float* b3    = (const float*)d_in[8];
    float* out = (float*)d_out;

    float* ws = (float*)d_ws;
    float* A   = ws;                          // FLAT float4 = 405504 floats
    float* B   = A + (size_t)BATCH * FLAT;
    float* P1  = B + (size_t)BATCH * FLAT;    // 768*4096 = 3.15M floats
    float* H1  = P1 + (size_t)NSLICES * 4096; // 4096
    float* P2  = H1 + 4096;                   // 32*512 = 16384

    k_step<true ><<<NTILE, 256, 0, stream>>>(nullptr, vin, frame, syn, (float4*)A);
    k_step<false><<<NTILE, 256, 0, stream>>>((const float4*)A, nullptr, nullptr, syn, (float4*)B);
    k_step<false><<<NTILE, 256, 0, stream>>>((const float4*)B, nullptr, nullptr, syn, (float4*)A);
    k_step<false><<<NTILE, 256, 0, stream>>>((const float4*)A, nullptr, nullptr, syn, (float4*)B);
    k_step<false><<<NTILE, 256, 0, stream>>>((const float4*)B, nullptr, nullptr, syn, (float4*)A);

    k_mlp1<<<NSLICES, 256, 0, stream>>>((const float4*)A, W1, P1);
    k_reduce1<<<256, 256, 0, stream>>>(P1, b1, H1);
    k_mlp2<<<64, 64, 0, stream>>>(H1, W2, P2);
    k_mlp3<<<1, 128, 0, stream>>>(P2, b2, W3, b3, out);
}